// Round 15
// baseline (220.688 us; speedup 1.0000x reference)
//
#include <hip/hip_runtime.h>
#include <hip/hip_fp16.h>
#include <math.h>

#define HH 480
#define WW 640
#define RAD 8
#define KK 17
#define DD 128
#define HWPIX (HH*WW)       // 307200
#define NBLK (HWPIX/256)    // 1200 exactly
#define TS 80               // x-tile width in rowsweep
#define XT 8                // tiles per row (XT*TS == WW)
#define ECAP 1024           // LDS event-stage capacity (floats); avg strip load ~160

static inline size_t al256(size_t x){ return (x + 255) & ~(size_t)255; }

// ================= batched counting-sort machinery (events + queries, validated v10/v12) ======
__global__ void hist_dual_kernel(const int* __restrict__ ey, const int* __restrict__ ex, int N,
                                 const int* __restrict__ qy, const int* __restrict__ qx, int M,
                                 unsigned* __restrict__ off, unsigned* __restrict__ qoff) {
    int e = blockIdx.x*blockDim.x + threadIdx.x;
    if (blockIdx.y == 0) {
        if (e < N) atomicAdd(&off[ey[e]*WW + ex[e]], 1u);
    } else {
        if (e < M) atomicAdd(&qoff[qy[e]*WW + qx[e]], 1u);
    }
}

__global__ void scan1_dual_kernel(unsigned* __restrict__ o0, unsigned* __restrict__ o1,
                                  unsigned* __restrict__ bs) {
    __shared__ unsigned sh[256];
    int t = threadIdx.x, b = blockIdx.x;
    unsigned* off = (b < NBLK) ? o0 : o1;
    int bb = (b < NBLK) ? b : b - NBLK;
    unsigned v = off[bb*256 + t];
    sh[t] = v; __syncthreads();
    for (int st = 1; st < 256; st <<= 1) {
        unsigned a = (t >= st) ? sh[t-st] : 0u;
        __syncthreads();
        sh[t] += a;
        __syncthreads();
    }
    off[bb*256 + t] = sh[t] - v;          // exclusive within block
    if (t == 255) bs[b] = sh[255];
}

// blocks 0,1: segment scans; block 2 (if do_tabs): per-dim constant tables
__global__ void scan2_dual_kernel(unsigned* __restrict__ bs_all,
                                  const float* __restrict__ Yw, const float* __restrict__ Xw,
                                  float4* __restrict__ wtab, float4* __restrict__ xtab0,
                                  float4* __restrict__ xtab1, int do_tabs) {
    if (blockIdx.x == 2) {
        if (!do_tabs) return;
        int d = threadIdx.x;
        if (d >= DD) return;
        float s, c, Yd = Yw[d];
        sincosf(-Yd, &s, &c);
        float sst, cst;
        sincosf(Yd * 0.125f, &sst, &cst);
        wtab[d] = make_float4(c, s, cst, sst);
        float th = Xw[d] * 0.125f;
        float s1, c1, s8, c8, s9, c9;
        sincosf(th, &s1, &c1);
        sincosf(8.f*th, &s8, &c8);
        sincosf(9.f*th, &s9, &c9);
        xtab0[d] = make_float4(c1, s1, c8, -s8);
        xtab1[d] = make_float4(c9, s9, 0.f, 0.f);
        return;
    }
    __shared__ unsigned sh[256];
    __shared__ unsigned carry;
    unsigned* bs = bs_all + blockIdx.x*NBLK;
    int t = threadIdx.x;
    if (t == 0) carry = 0u;
    __syncthreads();
    for (int base = 0; base < NBLK; base += 256) {
        int i = base + t;
        unsigned v = (i < NBLK) ? bs[i] : 0u;
        sh[t] = v; __syncthreads();
        for (int st = 1; st < 256; st <<= 1) {
            unsigned a = (t >= st) ? sh[t-st] : 0u;
            __syncthreads();
            sh[t] += a;
            __syncthreads();
        }
        unsigned tot = sh[255];
        if (i < NBLK) bs[i] = (sh[t] - v) + carry;
        __syncthreads();
        if (t == 0) carry += tot;
        __syncthreads();
    }
}

__global__ void scan3_dual_kernel(unsigned* __restrict__ o0, unsigned* __restrict__ o1,
                                  const unsigned* __restrict__ bs) {
    int b = blockIdx.x;
    unsigned* off = (b < NBLK) ? o0 : o1;
    int bb = (b < NBLK) ? b : b - NBLK;
    off[bb*256 + threadIdx.x] += bs[b];
}

// leaves off[pix] = END of bucket; start = pix ? off[pix-1] : 0
// main path: only tss needed (xs consumed solely by the fallback)
__global__ void sort_t_kernel(const int* __restrict__ ey, const int* __restrict__ ex,
                              const float* __restrict__ t, unsigned* __restrict__ off,
                              float* __restrict__ tss, int N) {
    int e = blockIdx.x*blockDim.x + threadIdx.x;
    if (e >= N) return;
    int pix = ey[e]*WW + ex[e];
    unsigned pos = atomicAdd(&off[pix], 1u);
    tss[pos] = t[e];
}

// fallback path: tss + xs
__global__ void sort_kernel(const int* __restrict__ ey, const int* __restrict__ ex,
                            const float* __restrict__ t, unsigned* __restrict__ off,
                            float* __restrict__ tss, int* __restrict__ xs, int N) {
    int e = blockIdx.x*blockDim.x + threadIdx.x;
    if (e >= N) return;
    int pix = ey[e]*WW + ex[e];
    unsigned pos = atomicAdd(&off[pix], 1u);
    tss[pos] = t[e];
    xs[pos]  = ex[e];
}

// query pixel-sort + per-query window count in one pass (off must be post-sort)
__global__ void qsortcnt_kernel(const int* __restrict__ qy, const int* __restrict__ qx,
                                unsigned* __restrict__ qoff, unsigned* __restrict__ qidx,
                                const unsigned* __restrict__ off, float* __restrict__ qcnt, int M) {
    int q = blockIdx.x*blockDim.x + threadIdx.x;
    if (q >= M) return;
    int cy = qy[q], cx = qx[q];
    int pix = cy*WW + cx;
    unsigned pos = atomicAdd(&qoff[pix], 1u);
    qidx[pos] = q;
    int xlo = cx - RAD; if (xlo < 0) xlo = 0;
    int xhi = cx + RAD; if (xhi > WW-1) xhi = WW-1;
    unsigned s = 0;
    for (int i = 0; i < KK; ++i) {
        int yy = cy + i - RAD;
        if ((unsigned)yy >= HH) continue;
        int plo = yy*WW + xlo, phi = yy*WW + xhi;
        unsigned st = plo ? off[plo-1] : 0u;
        s += off[phi] - st;
    }
    qcnt[q] = (float)s;
}

// ================= fused build+convh: sliding-DFT row sweep + LDS event staging ===============
// H[hrow][x][dd] (packed half2) for image row hy = rb0 + hrow (zero outside image).
// Recurrence (fp32 internal): H[x+1] = e^{-i th} (H[x] - e^{-8i th} G[x-8] + e^{9i th} G[x+9])
// v15: the block's full event window [st0,en_tot) and off-row segment are staged into LDS
// up front with coalesced bursts -> the serial sweep touches only LDS (no global latency chain).
__global__ __launch_bounds__(128) void rowsweep_kernel(
        const unsigned* __restrict__ off, const float* __restrict__ tss,
        const float* __restrict__ Tw, const float4* __restrict__ xtab0,
        const float4* __restrict__ xtab1, __half2* __restrict__ Hout, int rb0) {
    __shared__ __half2 ring[KK][DD];     // 17-deep G history, packed (gr,gi)
    __shared__ unsigned soff[TS + 18 + 2]; // off row segment [cfirst-1, clast]
    __shared__ float elds[ECAP];         // staged event times
    int dd   = threadIdx.x;
    int hrow = blockIdx.y;
    int hy   = rb0 + hrow;
    int x0   = blockIdx.x * TS;
    int x1   = x0 + TS; if (x1 > WW) x1 = WW;
    __half2* hp = Hout + (long long)hrow*WW*DD + dd;

    if ((unsigned)hy >= HH) {                       // zero-pad rows (whole block exits)
        __half2 z = __floats2half2_rn(0.f, 0.f);
        for (int x = x0; x < x1; ++x) hp[(long long)x*DD] = z;
        return;
    }

    const int rowbase = hy*WW;
    int cfirst = x0 - RAD;   if (cfirst < 0) cfirst = 0;
    int clast  = x1 + RAD-1; if (clast > WW-1) clast = WW-1;
    int lo     = rowbase + cfirst - 1;              // may be -1 when rowbase==0 && cfirst==0
    int nseg   = rowbase + clast - lo + 1;          // <= TS+18

    for (int i = dd; i < nseg; i += 128)
        soff[i] = (lo + i >= 0) ? off[lo + i] : 0u;
    __syncthreads();
    unsigned st0    = soff[0];
    unsigned en_tot = soff[nseg - 1];
    int ecnt = (int)(en_tot - st0);
    for (int i = dd; i < ecnt && i < ECAP; i += 128)
        elds[i] = tss[st0 + i];
    __syncthreads();

    float Td = Tw[dd];
    float4 t0 = xtab0[dd], t1 = xtab1[dd];
    const float er_ = t0.x,  ei_ = t0.y;    // e^{+i th}  (init weight step)
    const float ar  = t0.x,  ai  = -t0.y;   // e^{-i th}  (recurrence rotation)
    const float w0r = t0.z,  w0i = t0.w;    // e^{-8 i th}
    const float w17r = t1.x, w17i = t1.y;   // e^{+9 i th}

#define GAT(col, gr, gi)                                                    \
    {                                                                       \
        gr = 0.f; gi = 0.f;                                                 \
        if ((unsigned)(col) < WW) {                                         \
            int pix_ = rowbase + (col);                                     \
            unsigned st_ = soff[pix_ - 1 - lo];                             \
            unsigned en_ = soff[pix_ - lo];                                 \
            for (unsigned p_ = st_; p_ < en_; ++p_) {                       \
                unsigned ix_ = p_ - st0;                                    \
                float tv_ = (ix_ < ECAP) ? elds[ix_] : tss[p_];             \
                float ss_, cc_;                                             \
                __sincosf(tv_*Td, &ss_, &cc_);                              \
                gr += cc_; gi += ss_;                                       \
            }                                                               \
        }                                                                   \
    }

    // init: H[x0] direct 17-tap, fill ring with G[x0-8 .. x0+8]
    float hr = 0.f, hi = 0.f;
    float wr = w0r, wi = w0i;
    #pragma unroll
    for (int j = 0; j < KK; ++j) {
        float gr, gi; GAT(x0 + j - RAD, gr, gi);
        hr = fmaf(gr, wr, hr); hr = fmaf(-gi, wi, hr);
        hi = fmaf(gr, wi, hi); hi = fmaf(gi, wr, hi);
        ring[j][dd] = __floats2half2_rn(gr, gi);
        float nr = wr*er_ - wi*ei_;
        wi       = wr*ei_ + wi*er_;
        wr       = nr;
    }
    hp[(long long)x0*DD] = __floats2half2_rn(hr, hi);

    int ri = 0;
    for (int xn = x0 + 1; xn < x1; ++xn) {
        float gr, gi; GAT(xn + RAD, gr, gi);            // G[xn+8] (new)
        float2 go = __half22float2(ring[ri][dd]);       // G[xn-9] (old)
        ring[ri][dd] = __floats2half2_rn(gr, gi);
        ri = (ri + 1 == KK) ? 0 : ri + 1;
        float tr = hr - (go.x*w0r - go.y*w0i) + (gr*w17r - gi*w17i);
        float ti = hi - (go.x*w0i + go.y*w0r) + (gr*w17i + gi*w17r);
        hr = tr*ar - ti*ai;
        hi = tr*ai + ti*ar;
        hp[(long long)xn*DD] = __floats2half2_rn(hr, hi);
    }
#undef GAT
}

// ================= stage 2: 17-tap vertical gather on half2 H, 2 dims/lane (validated v13) ====
__global__ __launch_bounds__(256) void query_sep_kernel(
        const unsigned* __restrict__ qidx, const int* __restrict__ qy,
        const int* __restrict__ qx, const float* __restrict__ qt,
        const float* __restrict__ Tw, const float4* __restrict__ wtab,
        const unsigned* __restrict__ H, const float* __restrict__ qcnt,
        float* __restrict__ out, int M, int r0, int band, int rb0,
        long long out_n, int real_only) {
    int lt   = threadIdx.x;
    int p    = blockIdx.x*4 + (lt >> 6);
    int lane = lt & 63;
    if (p >= M) return;
    int q = (int)qidx[p];
    int cy = qy[q];
    if (cy < r0 || cy >= r0 + band) return;
    int cx = qx[q];
    int d0 = lane*2, d1 = d0 + 1;

    float4 w0 = wtab[d0], w1 = wtab[d1];
    float wyr0 = w0.x, wyi0 = w0.y, cst0 = w0.z, sst0 = w0.w;
    float wyr1 = w1.x, wyi1 = w1.y, cst1 = w1.z, sst1 = w1.w;

    const unsigned* hp = H + ((long long)(cy - RAD - rb0)*WW + cx)*DD + d0;
    float er0 = 0.f, ei0 = 0.f, er1 = 0.f, ei1 = 0.f;
    #pragma unroll
    for (int i = 0; i < KK; ++i) {
        uint2 v = *(const uint2*)(hp + (long long)i*WW*DD);
        float2 f0 = __half22float2(*(const __half2*)&v.x);
        float2 f1 = __half22float2(*(const __half2*)&v.y);
        er0 = fmaf(f0.x, wyr0, er0); er0 = fmaf(-f0.y, wyi0, er0);
        ei0 = fmaf(f0.x, wyi0, ei0); ei0 = fmaf(f0.y, wyr0, ei0);
        er1 = fmaf(f1.x, wyr1, er1); er1 = fmaf(-f1.y, wyi1, er1);
        ei1 = fmaf(f1.x, wyi1, ei1); ei1 = fmaf(f1.y, wyr1, ei1);
        float nr;
        nr = wyr0*cst0 - wyi0*sst0; wyi0 = wyr0*sst0 + wyi0*cst0; wyr0 = nr;
        nr = wyr1*cst1 - wyi1*sst1; wyi1 = wyr1*sst1 + wyi1*cst1; wyr1 = nr;
    }

    float inv = 1.0f / fmaxf(qcnt[q], 1.0f);
    float s, c, qtv = qt[q];
    __sincosf(qtv * Tw[d0], &s, &c);
    float outr0 = (er0*c + ei0*s) * inv, outi0 = (ei0*c - er0*s) * inv;
    __sincosf(qtv * Tw[d1], &s, &c);
    float outr1 = (er1*c + ei1*s) * inv, outi1 = (ei1*c - er1*s) * inv;

    long long base = (long long)q*DD + d0;
    if (real_only) {
        if (base + 1 < out_n) *(float2*)(out + base) = make_float2(outr0, outr1);
        else if (base < out_n) out[base] = outr0;
    } else if (2*base + 3 < out_n) {
        *(float4*)(out + 2*base) = make_float4(outr0, outi0, outr1, outi1);
    }
}

// ================= fallback: event-direct query (validated v4, 2.69 ms) =================
__global__ __launch_bounds__(256) void query_direct_kernel(
        const int* __restrict__ qy, const int* __restrict__ qx,
        const float* __restrict__ qt, const float* __restrict__ Tw,
        const float* __restrict__ Xw, const float* __restrict__ Yw,
        const unsigned* __restrict__ off, const float* __restrict__ tss,
        const int* __restrict__ xs, float* __restrict__ out,
        int M, long long out_n, int real_only) {
    __shared__ float2 swx[KK*DD];
    __shared__ float2 swy[KK*DD];
    int lt = threadIdx.x;
    for (int idx = lt; idx < KK*DD; idx += 256) {
        int j = idx / DD, dd = idx & (DD-1);
        float s, c;
        sincosf((float)(j - RAD) * 0.125f * Xw[dd], &s, &c);
        swx[idx] = make_float2(c, s);
        sincosf((float)(j - RAD) * 0.125f * Yw[dd], &s, &c);
        swy[idx] = make_float2(c, s);
    }
    __syncthreads();

    int q = blockIdx.x*2 + (lt >> 7);
    int d = lt & (DD-1);
    if (q >= M) return;

    int cy = qy[q], cx = qx[q];
    float Td = Tw[d];
    int xlo = cx - RAD; if (xlo < 0) xlo = 0;
    int xhi = cx + RAD; if (xhi > WW-1) xhi = WW-1;

    float accr = 0.f, acci = 0.f;
    unsigned cnt = 0;
    for (int i = 0; i < KK; ++i) {
        int yy = cy + i - RAD;
        if ((unsigned)yy >= HH) continue;
        int plo = yy*WW + xlo, phi = yy*WW + xhi;
        unsigned st = plo ? off[plo-1] : 0u;
        unsigned en = off[phi];
        cnt += en - st;
        float rr = 0.f, ri = 0.f;
        for (unsigned p = st; p < en; ++p) {
            float te = tss[p];
            int   xe = xs[p];
            float2 wx = swx[(xe - cx + RAD)*DD + d];
            float s, c;
            __sincosf(te * Td, &s, &c);
            rr = fmaf(c, wx.x, rr); rr = fmaf(-s, wx.y, rr);
            ri = fmaf(c, wx.y, ri); ri = fmaf(s, wx.x, ri);
        }
        float2 wy = swy[i*DD + d];
        accr = fmaf(rr, wy.x, accr); accr = fmaf(-ri, wy.y, accr);
        acci = fmaf(rr, wy.y, acci); acci = fmaf(ri, wy.x, acci);
    }

    float s, c;
    sincosf(qt[q] * Td, &s, &c);
    float inv = 1.0f / fmaxf((float)cnt, 1.0f);
    float outr = (accr*c + acci*s) * inv;
    float outi = (acci*c - accr*s) * inv;
    long long base = (long long)q*DD + d;
    if (real_only) { if (base < out_n) out[base] = outr; }
    else if (2*base + 1 < out_n) { out[2*base] = outr; out[2*base+1] = outi; }
}

extern "C" void kernel_launch(void* const* d_in, const int* in_sizes, int n_in,
                              void* d_out, int out_size, void* d_ws, size_t ws_size,
                              hipStream_t stream) {
    const float* t  = (const float*)d_in[0];
    const int*   ey = (const int*)d_in[1];
    const int*   ex = (const int*)d_in[2];
    const int*   qy = (const int*)d_in[3];
    const int*   qx = (const int*)d_in[4];
    const float* qt = (const float*)d_in[5];
    const float* Tw = (const float*)d_in[6];
    const float* Xw = (const float*)d_in[7];
    const float* Yw = (const float*)d_in[8];

    int N = in_sizes[0];
    int M = in_sizes[3];

    // ws: [off | qoff | bs(2 segs) | tss | xs | qidx | qcnt | wtab | xtab0 | xtab1 | H band]
    size_t off_b  = al256((size_t)HWPIX*4);
    size_t qoff_b = al256((size_t)HWPIX*4);
    size_t bs_b   = al256((size_t)2*NBLK*4);
    size_t tss_b  = al256((size_t)N*4);
    size_t xs_b   = al256((size_t)N*4);
    size_t qidx_b = al256((size_t)M*4);
    size_t qc_b   = al256((size_t)M*4);
    size_t wt_b   = al256((size_t)DD*16);
    size_t xt_b   = al256((size_t)DD*16);
    size_t fixed  = off_b + qoff_b + bs_b + tss_b + xs_b + qidx_b + qc_b + wt_b + 2*xt_b;
    size_t need_min = off_b + qoff_b + bs_b + tss_b + xs_b;

    if (ws_size < need_min || d_ws == nullptr) {
        hipMemsetAsync(d_out, 0, (size_t)out_size*4, stream);   // safe diagnostic
        return;
    }

    char*     ws   = (char*)d_ws;
    unsigned* off  = (unsigned*)ws;
    unsigned* qoff = (unsigned*)(ws + off_b);
    unsigned* bs   = (unsigned*)(ws + off_b + qoff_b);
    float*    tss  = (float*)(ws + off_b + qoff_b + bs_b);
    int*      xs   = (int*)(ws + off_b + qoff_b + bs_b + tss_b);
    unsigned* qidx = (unsigned*)(ws + off_b + qoff_b + bs_b + tss_b + xs_b);
    float*    qcnt = (float*)(ws + off_b + qoff_b + bs_b + tss_b + xs_b + qidx_b);
    float4*   wtab = (float4*)(ws + off_b + qoff_b + bs_b + tss_b + xs_b + qidx_b + qc_b);
    float4*   xtab0= (float4*)(ws + off_b + qoff_b + bs_b + tss_b + xs_b + qidx_b + qc_b + wt_b);
    float4*   xtab1= (float4*)(ws + off_b + qoff_b + bs_b + tss_b + xs_b + qidx_b + qc_b + wt_b + xt_b);
    __half2*  H    = (__half2*)(ws + fixed);

    long long full = (long long)M * DD;
    int real_only = (out_size < 2*full) ? 1 : 0;

    // ---- band sizing first (host arithmetic): decides which sort variant we need ----
    long long band_sz = 0;
    if (ws_size > fixed) {
        long long hrows_fit = (long long)((ws_size - fixed) / ((size_t)WW*DD*4));
        band_sz = hrows_fit - 16;
        if (band_sz > HH) band_sz = HH;
    }
    int do_tabs = (band_sz >= 32) ? 1 : 0;

    // ---- batched event+query counting sort (off and qoff adjacent: one memset) ----
    hipMemsetAsync(off, 0, off_b + (size_t)HWPIX*4, stream);
    int hb = ((N > M ? N : M) + 255)/256;
    hist_dual_kernel<<<dim3(hb, 2), 256, 0, stream>>>(ey, ex, N, qy, qx, M, off, qoff);
    scan1_dual_kernel<<<2*NBLK, 256, 0, stream>>>(off, qoff, bs);
    scan2_dual_kernel<<<3, 256, 0, stream>>>(bs, Yw, Xw, wtab, xtab0, xtab1, do_tabs);
    scan3_dual_kernel<<<2*NBLK, 256, 0, stream>>>(off, qoff, bs);

    if (!do_tabs) {
        // fallback needs xs too
        sort_kernel<<<(N+255)/256, 256, 0, stream>>>(ey, ex, t, off, tss, xs, N);
        query_direct_kernel<<<(M+1)/2, 256, 0, stream>>>(
            qy, qx, qt, Tw, Xw, Yw, off, tss, xs, (float*)d_out,
            M, (long long)out_size, real_only);
        return;
    }

    // main path: tss-only sort (xs unused downstream)
    sort_t_kernel<<<(N+255)/256, 256, 0, stream>>>(ey, ex, t, off, tss, N);

    // query pixel-sort + window counts (off is post-sort here)
    qsortcnt_kernel<<<(M+255)/256, 256, 0, stream>>>(qy, qx, qoff, qidx, off, qcnt, M);

    // ---- banded sweep + gather ----
    for (int r0 = 0; r0 < HH; r0 += (int)band_sz) {
        int band  = (HH - r0 < band_sz) ? (HH - r0) : (int)band_sz;
        int hrows = band + 16;
        dim3 g(XT, hrows);
        rowsweep_kernel<<<g, 128, 0, stream>>>(off, tss, Tw, xtab0, xtab1, H, r0 - RAD);
        query_sep_kernel<<<(M+3)/4, 256, 0, stream>>>(
            qidx, qy, qx, qt, Tw, wtab, (const unsigned*)H, qcnt, (float*)d_out,
            M, r0, band, r0 - RAD, (long long)out_size, real_only);
    }
}

// Round 16
// 209.801 us; speedup vs baseline: 1.0519x; 1.0519x over previous
//
#include <hip/hip_runtime.h>
#include <hip/hip_fp16.h>
#include <math.h>

#define HH 480
#define WW 640
#define RAD 8
#define KK 17
#define DD 128
#define HWPIX (HH*WW)       // 307200
#define NBLK (HWPIX/256)    // 1200 exactly
#define TS 80               // x-tile width in rowsweep
#define XT 8                // tiles per row (XT*TS == WW)

static inline size_t al256(size_t x){ return (x + 255) & ~(size_t)255; }

// ================= batched counting-sort machinery (events + queries, validated v10/v12) ======
__global__ void hist_dual_kernel(const int* __restrict__ ey, const int* __restrict__ ex, int N,
                                 const int* __restrict__ qy, const int* __restrict__ qx, int M,
                                 unsigned* __restrict__ off, unsigned* __restrict__ qoff) {
    int e = blockIdx.x*blockDim.x + threadIdx.x;
    if (blockIdx.y == 0) {
        if (e < N) atomicAdd(&off[ey[e]*WW + ex[e]], 1u);
    } else {
        if (e < M) atomicAdd(&qoff[qy[e]*WW + qx[e]], 1u);
    }
}

__global__ void scan1_dual_kernel(unsigned* __restrict__ o0, unsigned* __restrict__ o1,
                                  unsigned* __restrict__ bs) {
    __shared__ unsigned sh[256];
    int t = threadIdx.x, b = blockIdx.x;
    unsigned* off = (b < NBLK) ? o0 : o1;
    int bb = (b < NBLK) ? b : b - NBLK;
    unsigned v = off[bb*256 + t];
    sh[t] = v; __syncthreads();
    for (int st = 1; st < 256; st <<= 1) {
        unsigned a = (t >= st) ? sh[t-st] : 0u;
        __syncthreads();
        sh[t] += a;
        __syncthreads();
    }
    off[bb*256 + t] = sh[t] - v;          // exclusive within block
    if (t == 255) bs[b] = sh[255];
}

// blocks 0,1: segment scans; block 2 (if do_tabs): per-dim constant tables
__global__ void scan2_dual_kernel(unsigned* __restrict__ bs_all,
                                  const float* __restrict__ Yw, const float* __restrict__ Xw,
                                  float4* __restrict__ wtab, float4* __restrict__ xtab0,
                                  float4* __restrict__ xtab1, int do_tabs) {
    if (blockIdx.x == 2) {
        if (!do_tabs) return;
        int d = threadIdx.x;
        if (d >= DD) return;
        float s, c, Yd = Yw[d];
        sincosf(-Yd, &s, &c);
        float sst, cst;
        sincosf(Yd * 0.125f, &sst, &cst);
        wtab[d] = make_float4(c, s, cst, sst);
        float th = Xw[d] * 0.125f;
        float s1, c1, s8, c8, s9, c9;
        sincosf(th, &s1, &c1);
        sincosf(8.f*th, &s8, &c8);
        sincosf(9.f*th, &s9, &c9);
        xtab0[d] = make_float4(c1, s1, c8, -s8);
        xtab1[d] = make_float4(c9, s9, 0.f, 0.f);
        return;
    }
    __shared__ unsigned sh[256];
    __shared__ unsigned carry;
    unsigned* bs = bs_all + blockIdx.x*NBLK;
    int t = threadIdx.x;
    if (t == 0) carry = 0u;
    __syncthreads();
    for (int base = 0; base < NBLK; base += 256) {
        int i = base + t;
        unsigned v = (i < NBLK) ? bs[i] : 0u;
        sh[t] = v; __syncthreads();
        for (int st = 1; st < 256; st <<= 1) {
            unsigned a = (t >= st) ? sh[t-st] : 0u;
            __syncthreads();
            sh[t] += a;
            __syncthreads();
        }
        unsigned tot = sh[255];
        if (i < NBLK) bs[i] = (sh[t] - v) + carry;
        __syncthreads();
        if (t == 0) carry += tot;
        __syncthreads();
    }
}

__global__ void scan3_dual_kernel(unsigned* __restrict__ o0, unsigned* __restrict__ o1,
                                  const unsigned* __restrict__ bs) {
    int b = blockIdx.x;
    unsigned* off = (b < NBLK) ? o0 : o1;
    int bb = (b < NBLK) ? b : b - NBLK;
    off[bb*256 + threadIdx.x] += bs[b];
}

// leaves off[pix] = END of bucket; start = pix ? off[pix-1] : 0
// main path: only tss needed (xs consumed solely by the fallback)
__global__ void sort_t_kernel(const int* __restrict__ ey, const int* __restrict__ ex,
                              const float* __restrict__ t, unsigned* __restrict__ off,
                              float* __restrict__ tss, int N) {
    int e = blockIdx.x*blockDim.x + threadIdx.x;
    if (e >= N) return;
    int pix = ey[e]*WW + ex[e];
    unsigned pos = atomicAdd(&off[pix], 1u);
    tss[pos] = t[e];
}

// fallback path: tss + xs
__global__ void sort_kernel(const int* __restrict__ ey, const int* __restrict__ ex,
                            const float* __restrict__ t, unsigned* __restrict__ off,
                            float* __restrict__ tss, int* __restrict__ xs, int N) {
    int e = blockIdx.x*blockDim.x + threadIdx.x;
    if (e >= N) return;
    int pix = ey[e]*WW + ex[e];
    unsigned pos = atomicAdd(&off[pix], 1u);
    tss[pos] = t[e];
    xs[pos]  = ex[e];
}

// slim query pixel-sort: scatter only (window count folded into query_sep, v16)
__global__ void qsort_kernel(const int* __restrict__ qy, const int* __restrict__ qx,
                             unsigned* __restrict__ qoff, unsigned* __restrict__ qidx, int M) {
    int q = blockIdx.x*blockDim.x + threadIdx.x;
    if (q >= M) return;
    int pix = qy[q]*WW + qx[q];
    unsigned pos = atomicAdd(&qoff[pix], 1u);
    qidx[pos] = q;
}

// ================= fused build+convh: sliding-DFT row sweep (validated v14 form) =============
// H[hrow][x][dd] (packed half2) for image row hy = rb0 + hrow (zero outside image).
// Recurrence (fp32 internal): H[x+1] = e^{-i th} (H[x] - e^{-8i th} G[x-8] + e^{9i th} G[x+9])
__global__ __launch_bounds__(128) void rowsweep_kernel(
        const unsigned* __restrict__ off, const float* __restrict__ tss,
        const float* __restrict__ Tw, const float4* __restrict__ xtab0,
        const float4* __restrict__ xtab1, __half2* __restrict__ Hout, int rb0) {
    __shared__ __half2 ring[KK][DD];   // 17-deep G history, packed (gr,gi)
    int dd   = threadIdx.x;
    int hrow = blockIdx.y;
    int hy   = rb0 + hrow;
    int x0   = blockIdx.x * TS;
    int x1   = x0 + TS; if (x1 > WW) x1 = WW;
    __half2* hp = Hout + (long long)hrow*WW*DD + dd;

    if ((unsigned)hy >= HH) {                       // zero-pad rows
        __half2 z = __floats2half2_rn(0.f, 0.f);
        for (int x = x0; x < x1; ++x) hp[(long long)x*DD] = z;
        return;
    }

    float Td = Tw[dd];
    float4 t0 = xtab0[dd], t1 = xtab1[dd];
    const float er_ = t0.x,  ei_ = t0.y;    // e^{+i th}  (init weight step)
    const float ar  = t0.x,  ai  = -t0.y;   // e^{-i th}  (recurrence rotation)
    const float w0r = t0.z,  w0i = t0.w;    // e^{-8 i th}
    const float w17r = t1.x, w17i = t1.y;   // e^{+9 i th}

    const int rowbase = hy*WW;
    const unsigned* offr = off + rowbase;

#define GAT(col, gr, gi)                                                    \
    {                                                                       \
        gr = 0.f; gi = 0.f;                                                 \
        if ((unsigned)(col) < WW) {                                         \
            int pix_ = rowbase + (col);                                     \
            unsigned st_ = pix_ ? off[pix_-1] : 0u;                         \
            unsigned en_ = offr[(col)];                                     \
            for (unsigned p_ = st_; p_ < en_; ++p_) {                       \
                float ss_, cc_;                                             \
                __sincosf(tss[p_]*Td, &ss_, &cc_);                          \
                gr += cc_; gi += ss_;                                       \
            }                                                               \
        }                                                                   \
    }

    // init: H[x0] direct 17-tap, fill ring with G[x0-8 .. x0+8]
    float hr = 0.f, hi = 0.f;
    float wr = w0r, wi = w0i;
    #pragma unroll
    for (int j = 0; j < KK; ++j) {
        float gr, gi; GAT(x0 + j - RAD, gr, gi);
        hr = fmaf(gr, wr, hr); hr = fmaf(-gi, wi, hr);
        hi = fmaf(gr, wi, hi); hi = fmaf(gi, wr, hi);
        ring[j][dd] = __floats2half2_rn(gr, gi);
        float nr = wr*er_ - wi*ei_;
        wi       = wr*ei_ + wi*er_;
        wr       = nr;
    }
    hp[(long long)x0*DD] = __floats2half2_rn(hr, hi);

    int ri = 0;
    for (int xn = x0 + 1; xn < x1; ++xn) {
        float gr, gi; GAT(xn + RAD, gr, gi);            // G[xn+8] (new)
        float2 go = __half22float2(ring[ri][dd]);       // G[xn-9] (old)
        ring[ri][dd] = __floats2half2_rn(gr, gi);
        ri = (ri + 1 == KK) ? 0 : ri + 1;
        float tr = hr - (go.x*w0r - go.y*w0i) + (gr*w17r - gi*w17i);
        float ti = hi - (go.x*w0i + go.y*w0r) + (gr*w17i + gi*w17r);
        hr = tr*ar - ti*ai;
        hi = tr*ai + ti*ar;
        hp[(long long)xn*DD] = __floats2half2_rn(hr, hi);
    }
#undef GAT
}

// ================= stage 2: 17-tap vertical gather; in-wave window count (v16) ================
__global__ __launch_bounds__(256) void query_sep_kernel(
        const unsigned* __restrict__ qidx, const int* __restrict__ qy,
        const int* __restrict__ qx, const float* __restrict__ qt,
        const float* __restrict__ Tw, const float4* __restrict__ wtab,
        const unsigned* __restrict__ H, const unsigned* __restrict__ off,
        float* __restrict__ out, int M, int r0, int band, int rb0,
        long long out_n, int real_only) {
    int lt   = threadIdx.x;
    int p    = blockIdx.x*4 + (lt >> 6);
    int lane = lt & 63;
    if (p >= M) return;
    int q = (int)qidx[p];
    int cy = qy[q];
    if (cy < r0 || cy >= r0 + band) return;
    int cx = qx[q];
    int d0 = lane*2, d1 = d0 + 1;

    // ---- in-wave window count: lanes 0..16 each handle one row (off is post-sort: END) ----
    unsigned part = 0;
    if (lane < KK) {
        int yy = cy + lane - RAD;
        if ((unsigned)yy < HH) {
            int xlo = cx - RAD; if (xlo < 0) xlo = 0;
            int xhi = cx + RAD; if (xhi > WW-1) xhi = WW-1;
            int plo = yy*WW + xlo, phi = yy*WW + xhi;
            unsigned st = plo ? off[plo-1] : 0u;
            part = off[phi] - st;
        }
    }
    for (int o = 32; o; o >>= 1) part += __shfl_down(part, o);
    float cnt = (float)__shfl(part, 0);

    float4 w0 = wtab[d0], w1 = wtab[d1];
    float wyr0 = w0.x, wyi0 = w0.y, cst0 = w0.z, sst0 = w0.w;
    float wyr1 = w1.x, wyi1 = w1.y, cst1 = w1.z, sst1 = w1.w;

    const unsigned* hp = H + ((long long)(cy - RAD - rb0)*WW + cx)*DD + d0;
    float er0 = 0.f, ei0 = 0.f, er1 = 0.f, ei1 = 0.f;
    #pragma unroll
    for (int i = 0; i < KK; ++i) {
        uint2 v = *(const uint2*)(hp + (long long)i*WW*DD);
        float2 f0 = __half22float2(*(const __half2*)&v.x);
        float2 f1 = __half22float2(*(const __half2*)&v.y);
        er0 = fmaf(f0.x, wyr0, er0); er0 = fmaf(-f0.y, wyi0, er0);
        ei0 = fmaf(f0.x, wyi0, ei0); ei0 = fmaf(f0.y, wyr0, ei0);
        er1 = fmaf(f1.x, wyr1, er1); er1 = fmaf(-f1.y, wyi1, er1);
        ei1 = fmaf(f1.x, wyi1, ei1); ei1 = fmaf(f1.y, wyr1, ei1);
        float nr;
        nr = wyr0*cst0 - wyi0*sst0; wyi0 = wyr0*sst0 + wyi0*cst0; wyr0 = nr;
        nr = wyr1*cst1 - wyi1*sst1; wyi1 = wyr1*sst1 + wyi1*cst1; wyr1 = nr;
    }

    float inv = 1.0f / fmaxf(cnt, 1.0f);
    float s, c, qtv = qt[q];
    __sincosf(qtv * Tw[d0], &s, &c);
    float outr0 = (er0*c + ei0*s) * inv, outi0 = (ei0*c - er0*s) * inv;
    __sincosf(qtv * Tw[d1], &s, &c);
    float outr1 = (er1*c + ei1*s) * inv, outi1 = (ei1*c - er1*s) * inv;

    long long base = (long long)q*DD + d0;
    if (real_only) {
        if (base + 1 < out_n) *(float2*)(out + base) = make_float2(outr0, outr1);
        else if (base < out_n) out[base] = outr0;
    } else if (2*base + 3 < out_n) {
        *(float4*)(out + 2*base) = make_float4(outr0, outi0, outr1, outi1);
    }
}

// ================= fallback: event-direct query (validated v4, 2.69 ms) =================
__global__ __launch_bounds__(256) void query_direct_kernel(
        const int* __restrict__ qy, const int* __restrict__ qx,
        const float* __restrict__ qt, const float* __restrict__ Tw,
        const float* __restrict__ Xw, const float* __restrict__ Yw,
        const unsigned* __restrict__ off, const float* __restrict__ tss,
        const int* __restrict__ xs, float* __restrict__ out,
        int M, long long out_n, int real_only) {
    __shared__ float2 swx[KK*DD];
    __shared__ float2 swy[KK*DD];
    int lt = threadIdx.x;
    for (int idx = lt; idx < KK*DD; idx += 256) {
        int j = idx / DD, dd = idx & (DD-1);
        float s, c;
        sincosf((float)(j - RAD) * 0.125f * Xw[dd], &s, &c);
        swx[idx] = make_float2(c, s);
        sincosf((float)(j - RAD) * 0.125f * Yw[dd], &s, &c);
        swy[idx] = make_float2(c, s);
    }
    __syncthreads();

    int q = blockIdx.x*2 + (lt >> 7);
    int d = lt & (DD-1);
    if (q >= M) return;

    int cy = qy[q], cx = qx[q];
    float Td = Tw[d];
    int xlo = cx - RAD; if (xlo < 0) xlo = 0;
    int xhi = cx + RAD; if (xhi > WW-1) xhi = WW-1;

    float accr = 0.f, acci = 0.f;
    unsigned cnt = 0;
    for (int i = 0; i < KK; ++i) {
        int yy = cy + i - RAD;
        if ((unsigned)yy >= HH) continue;
        int plo = yy*WW + xlo, phi = yy*WW + xhi;
        unsigned st = plo ? off[plo-1] : 0u;
        unsigned en = off[phi];
        cnt += en - st;
        float rr = 0.f, ri = 0.f;
        for (unsigned p = st; p < en; ++p) {
            float te = tss[p];
            int   xe = xs[p];
            float2 wx = swx[(xe - cx + RAD)*DD + d];
            float s, c;
            __sincosf(te * Td, &s, &c);
            rr = fmaf(c, wx.x, rr); rr = fmaf(-s, wx.y, rr);
            ri = fmaf(c, wx.y, ri); ri = fmaf(s, wx.x, ri);
        }
        float2 wy = swy[i*DD + d];
        accr = fmaf(rr, wy.x, accr); accr = fmaf(-ri, wy.y, accr);
        acci = fmaf(rr, wy.y, acci); acci = fmaf(ri, wy.x, acci);
    }

    float s, c;
    sincosf(qt[q] * Td, &s, &c);
    float inv = 1.0f / fmaxf((float)cnt, 1.0f);
    float outr = (accr*c + acci*s) * inv;
    float outi = (acci*c - accr*s) * inv;
    long long base = (long long)q*DD + d;
    if (real_only) { if (base < out_n) out[base] = outr; }
    else if (2*base + 1 < out_n) { out[2*base] = outr; out[2*base+1] = outi; }
}

extern "C" void kernel_launch(void* const* d_in, const int* in_sizes, int n_in,
                              void* d_out, int out_size, void* d_ws, size_t ws_size,
                              hipStream_t stream) {
    const float* t  = (const float*)d_in[0];
    const int*   ey = (const int*)d_in[1];
    const int*   ex = (const int*)d_in[2];
    const int*   qy = (const int*)d_in[3];
    const int*   qx = (const int*)d_in[4];
    const float* qt = (const float*)d_in[5];
    const float* Tw = (const float*)d_in[6];
    const float* Xw = (const float*)d_in[7];
    const float* Yw = (const float*)d_in[8];

    int N = in_sizes[0];
    int M = in_sizes[3];

    // ws: [off | qoff | bs(2 segs) | tss | xs | qidx | wtab | xtab0 | xtab1 | H band]
    size_t off_b  = al256((size_t)HWPIX*4);
    size_t qoff_b = al256((size_t)HWPIX*4);
    size_t bs_b   = al256((size_t)2*NBLK*4);
    size_t tss_b  = al256((size_t)N*4);
    size_t xs_b   = al256((size_t)N*4);
    size_t qidx_b = al256((size_t)M*4);
    size_t wt_b   = al256((size_t)DD*16);
    size_t xt_b   = al256((size_t)DD*16);
    size_t fixed  = off_b + qoff_b + bs_b + tss_b + xs_b + qidx_b + wt_b + 2*xt_b;
    size_t need_min = off_b + qoff_b + bs_b + tss_b + xs_b;

    if (ws_size < need_min || d_ws == nullptr) {
        hipMemsetAsync(d_out, 0, (size_t)out_size*4, stream);   // safe diagnostic
        return;
    }

    char*     ws   = (char*)d_ws;
    unsigned* off  = (unsigned*)ws;
    unsigned* qoff = (unsigned*)(ws + off_b);
    unsigned* bs   = (unsigned*)(ws + off_b + qoff_b);
    float*    tss  = (float*)(ws + off_b + qoff_b + bs_b);
    int*      xs   = (int*)(ws + off_b + qoff_b + bs_b + tss_b);
    unsigned* qidx = (unsigned*)(ws + off_b + qoff_b + bs_b + tss_b + xs_b);
    float4*   wtab = (float4*)(ws + off_b + qoff_b + bs_b + tss_b + xs_b + qidx_b);
    float4*   xtab0= (float4*)(ws + off_b + qoff_b + bs_b + tss_b + xs_b + qidx_b + wt_b);
    float4*   xtab1= (float4*)(ws + off_b + qoff_b + bs_b + tss_b + xs_b + qidx_b + wt_b + xt_b);
    __half2*  H    = (__half2*)(ws + fixed);

    long long full = (long long)M * DD;
    int real_only = (out_size < 2*full) ? 1 : 0;

    // ---- band sizing first (host arithmetic): decides which sort variant we need ----
    long long band_sz = 0;
    if (ws_size > fixed) {
        long long hrows_fit = (long long)((ws_size - fixed) / ((size_t)WW*DD*4));
        band_sz = hrows_fit - 16;
        if (band_sz > HH) band_sz = HH;
    }
    int do_tabs = (band_sz >= 32) ? 1 : 0;

    // ---- batched event+query counting sort (off and qoff adjacent: one memset) ----
    hipMemsetAsync(off, 0, off_b + (size_t)HWPIX*4, stream);
    int hb = ((N > M ? N : M) + 255)/256;
    hist_dual_kernel<<<dim3(hb, 2), 256, 0, stream>>>(ey, ex, N, qy, qx, M, off, qoff);
    scan1_dual_kernel<<<2*NBLK, 256, 0, stream>>>(off, qoff, bs);
    scan2_dual_kernel<<<3, 256, 0, stream>>>(bs, Yw, Xw, wtab, xtab0, xtab1, do_tabs);
    scan3_dual_kernel<<<2*NBLK, 256, 0, stream>>>(off, qoff, bs);

    if (!do_tabs) {
        // fallback needs xs too
        sort_kernel<<<(N+255)/256, 256, 0, stream>>>(ey, ex, t, off, tss, xs, N);
        query_direct_kernel<<<(M+1)/2, 256, 0, stream>>>(
            qy, qx, qt, Tw, Xw, Yw, off, tss, xs, (float*)d_out,
            M, (long long)out_size, real_only);
        return;
    }

    // main path: tss-only sort (xs unused downstream)
    sort_t_kernel<<<(N+255)/256, 256, 0, stream>>>(ey, ex, t, off, tss, N);

    // query pixel-sort (slim scatter; count folded into query_sep)
    qsort_kernel<<<(M+255)/256, 256, 0, stream>>>(qy, qx, qoff, qidx, M);

    // ---- banded sweep + gather ----
    for (int r0 = 0; r0 < HH; r0 += (int)band_sz) {
        int band  = (HH - r0 < band_sz) ? (HH - r0) : (int)band_sz;
        int hrows = band + 16;
        dim3 g(XT, hrows);
        rowsweep_kernel<<<g, 128, 0, stream>>>(off, tss, Tw, xtab0, xtab1, H, r0 - RAD);
        query_sep_kernel<<<(M+3)/4, 256, 0, stream>>>(
            qidx, qy, qx, qt, Tw, wtab, (const unsigned*)H, off, (float*)d_out,
            M, r0, band, r0 - RAD, (long long)out_size, real_only);
    }
}